// Round 8
// baseline (1895.060 us; speedup 1.0000x reference)
//
#include <hip/hip_runtime.h>
#include <hip/hip_bf16.h>
#include <math.h>

// Shapes (fixed): B=4, N=1024, SK=1024, D=1024, H=16, HD=64
typedef __attribute__((ext_vector_type(8))) short bf16x8;   // 8 bf16 (4 VGPRs)
typedef __attribute__((ext_vector_type(4))) float f32x4;

__device__ __forceinline__ void gll16(const void* g, const void* l) {
  // async global->LDS, 16B per lane; LDS dest = wave-uniform base + lane*16
  __builtin_amdgcn_global_load_lds((__attribute__((address_space(1))) void*)g,
                                   (__attribute__((address_space(3))) void*)l, 16, 0, 0);
}

__device__ __forceinline__ unsigned short bf16bits(float f) {
  __hip_bfloat16 h = __float2bfloat16(f);
  return *reinterpret_cast<unsigned short*>(&h);
}

// ---------- fused transpose of all 4 weight mats: fp32 (R x C) -> bf16 (C x R) ----------
__global__ __launch_bounds__(256) void k_transpose4(
    const float* __restrict__ W0, __hip_bfloat16* __restrict__ T0,
    const float* __restrict__ W1, __hip_bfloat16* __restrict__ T1,
    const float* __restrict__ W2, __hip_bfloat16* __restrict__ T2,
    const float* __restrict__ W3, __hip_bfloat16* __restrict__ T3)
{
  __shared__ float t[32][33];
  int b = blockIdx.x;
  const float* W; __hip_bfloat16* T; int R, C, bx, by;
  if (b < 1024)      { W = W0; T = T0; R = 1024; C = 1024; bx = b & 31;  by = b >> 5; }
  else if (b < 2048) { b -= 1024; W = W1; T = T1; R = 1024; C = 1024; bx = b & 31;  by = b >> 5; }
  else if (b < 6144) { b -= 2048; W = W2; T = T2; R = 1024; C = 4096; bx = b & 127; by = b >> 7; }
  else               { b -= 6144; W = W3; T = T3; R = 4096; C = 1024; bx = b & 31;  by = b >> 5; }
  const int c0 = bx << 5, r0 = by << 5;
  const int tx = threadIdx.x & 31, ty = threadIdx.x >> 5;  // ty 0..7
#pragma unroll
  for (int i = 0; i < 32; i += 8)
    t[ty + i][tx] = W[(size_t)(r0 + ty + i) * C + c0 + tx];
  __syncthreads();
#pragma unroll
  for (int i = 0; i < 32; i += 8)
    T[(size_t)(c0 + ty + i) * R + r0 + tx] = __float2bfloat16(t[tx][ty + i]);
}

// ---------- partial column sums of x: part[y][d] = sum_{r in y-th 128 rows} x[r][d] ----------
__global__ __launch_bounds__(256) void k_colsum_part(const float* __restrict__ x, float* __restrict__ part) {
  const int d = blockIdx.x * 256 + threadIdx.x;
  const int r0 = blockIdx.y * 128;
  float acc = 0.f;
  for (int r = 0; r < 128; ++r) acc += x[(size_t)(r0 + r) * 1024 + d];
  part[blockIdx.y * 1024 + d] = acc;
}

// ---------- t[j] = sum_d Xsum[d] * qkv_w[d][2048+j]  (Xsum recomputed in-block from part) ----------
__global__ __launch_bounds__(256) void k_matvec_t(const float* __restrict__ part,
                                                  const float* __restrict__ qkv_w,
                                                  float* __restrict__ tmpt) {
  __shared__ float xs[1024];
  __shared__ float red[8][32];
#pragma unroll
  for (int jj = 0; jj < 4; ++jj) {
    const int d = threadIdx.x + (jj << 8);
    float a = 0.f;
    for (int y = 0; y < 32; ++y) a += part[y * 1024 + d];
    xs[d] = a;
  }
  __syncthreads();
  const int j = blockIdx.x * 32 + (threadIdx.x & 31);
  const int rg = threadIdx.x >> 5;
  float acc = 0.f;
  for (int r = rg; r < 1024; r += 8)
    acc += xs[r] * qkv_w[(size_t)r * 3072 + 2048 + j];
  red[rg][threadIdx.x & 31] = acc;
  __syncthreads();
  if (threadIdx.x < 32) {
    float s = 0.f;
    for (int gq = 0; gq < 8; ++gq) s += red[gq][threadIdx.x];
    tmpt[blockIdx.x * 32 + threadIdx.x] = s;
  }
}

// ---------- sa_row[j] = sum_i Vsum[i&63]*sa_w[i][j] + sa_b[j]  (Vsum recomputed in-block) ----------
__global__ __launch_bounds__(256) void k_matvec_sa(const float* __restrict__ tmpt,
                                                   const float* __restrict__ qkv_b,
                                                   const float* __restrict__ saw,
                                                   const float* __restrict__ sab,
                                                   float* __restrict__ sarow) {
  __shared__ float vs[64];
  __shared__ float red[8][32];
  if (threadIdx.x < 64) {
    float a = 0.f;
    for (int h = 0; h < 16; ++h)
      a += tmpt[h * 64 + threadIdx.x] + 4096.0f * qkv_b[2048 + h * 64 + threadIdx.x];
    vs[threadIdx.x] = a;
  }
  __syncthreads();
  const int j = blockIdx.x * 32 + (threadIdx.x & 31);
  const int rg = threadIdx.x >> 5;
  float acc = 0.f;
  for (int r = rg; r < 1024; r += 8)
    acc += vs[r & 63] * saw[(size_t)r * 1024 + j];
  red[rg][threadIdx.x & 31] = acc;
  __syncthreads();
  if (threadIdx.x < 32) {
    float s = 0.f;
    for (int gq = 0; gq < 8; ++gq) s += red[gq][threadIdx.x];
    sarow[blockIdx.x * 32 + threadIdx.x] = s + sab[blockIdx.x * 32 + threadIdx.x];
  }
}

// ---------- LayerNorm (per-row, D=1024), float4-vectorized; y = LN(a [+b] [+c] [+rowadd]) ----------
__global__ __launch_bounds__(256) void k_ln(
    const float* __restrict__ a, const float* __restrict__ b, const float* __restrict__ c,
    const float* __restrict__ rowadd, const float* __restrict__ w,
    const float* __restrict__ bias, float* __restrict__ outF,
    __hip_bfloat16* __restrict__ outB)
{
  const size_t base = (size_t)blockIdx.x * 1024;
  const int d4 = threadIdx.x << 2;
  float4 t = *(const float4*)(a + base + d4);
  if (b) { const float4 u = *(const float4*)(b + base + d4);
           t.x += u.x; t.y += u.y; t.z += u.z; t.w += u.w; }
  if (c) { const float4 u = *(const float4*)(c + base + d4);
           t.x += u.x; t.y += u.y; t.z += u.z; t.w += u.w; }
  if (rowadd) { const float4 u = *(const float4*)(rowadd + d4);
                t.x += u.x; t.y += u.y; t.z += u.z; t.w += u.w; }
  float s1 = t.x + t.y + t.z + t.w;
  float s2 = t.x * t.x + t.y * t.y + t.z * t.z + t.w * t.w;
#pragma unroll
  for (int o = 32; o; o >>= 1) { s1 += __shfl_xor(s1, o); s2 += __shfl_xor(s2, o); }
  __shared__ float r1[4], r2[4];
  const int wv = threadIdx.x >> 6;
  if ((threadIdx.x & 63) == 0) { r1[wv] = s1; r2[wv] = s2; }
  __syncthreads();
  s1 = r1[0] + r1[1] + r1[2] + r1[3];
  s2 = r2[0] + r2[1] + r2[2] + r2[3];
  const float mean = s1 * (1.0f / 1024.0f);
  const float var = s2 * (1.0f / 1024.0f) - mean * mean;
  const float inv = rsqrtf(var + 1e-6f);
  const float4 w4 = *(const float4*)(w + d4);
  const float4 b4 = *(const float4*)(bias + d4);
  const float y0 = (t.x - mean) * inv * w4.x + b4.x;
  const float y1 = (t.y - mean) * inv * w4.y + b4.y;
  const float y2 = (t.z - mean) * inv * w4.z + b4.z;
  const float y3 = (t.w - mean) * inv * w4.w + b4.w;
  if (outF) *(float4*)(outF + base + d4) = make_float4(y0, y1, y2, y3);
  if (outB) {
    ushort4 u4; u4.x = bf16bits(y0); u4.y = bf16bits(y1); u4.z = bf16bits(y2); u4.w = bf16bits(y3);
    *(ushort4*)(outB + base + d4) = u4;
  }
}

// ---------- bf16 MFMA GEMM: C[M,N] = A[M,K] @ BT[N,K]^T + bias (m97 structure) ----------
// split-K via gridDim.z: z=0 -> outF+bias, z=1 -> outF2 no bias
template<int GELU, int OUTBF>
__global__ __launch_bounds__(256) void k_gemm_bt(
    const __hip_bfloat16* __restrict__ A, const __hip_bfloat16* __restrict__ BT,
    const float* __restrict__ bias, float* __restrict__ outF, float* __restrict__ outF2,
    __hip_bfloat16* __restrict__ outB, int M, int N, int K)
{
  __shared__ __align__(16) __hip_bfloat16 As[128 * 32];
  __shared__ __align__(16) __hip_bfloat16 Bs[128 * 32];
  const int tid = threadIdx.x;
  const int wave = tid >> 6, lane = tid & 63;
  const int m0 = blockIdx.y << 7, n0 = blockIdx.x << 7;
  const int kl = K / gridDim.z;
  const int ks = blockIdx.z * kl;
  float* outP = blockIdx.z ? outF2 : outF;
  const bool doBias = (blockIdx.z == 0);
  const int wr = wave >> 1, wc = wave & 1;         // 64x64 wave tile
  const int fr = lane & 15, fq = lane >> 4;
  f32x4 acc[4][4] = {};
  const int srow = (lane >> 2);                    // 0..15 within chunk
  const int scol = (lane & 3) * 8;                 // bf16 col offset
  for (int k0 = ks; k0 < ks + kl; k0 += 32) {
#pragma unroll
    for (int i = 0; i < 2; ++i) {
      const int chunk = wave * 2 + i;              // 0..7: 16 rows each
      const int row = (chunk << 4) + srow;
      gll16(A + (size_t)(m0 + row) * K + k0 + scol, As + (chunk << 9));
      gll16(BT + (size_t)(n0 + row) * K + k0 + scol, Bs + (chunk << 9));
    }
    __syncthreads();
    bf16x8 af[4], bfr[4];
#pragma unroll
    for (int m = 0; m < 4; ++m)
      af[m] = *(const bf16x8*)(As + ((wr << 6) + (m << 4) + fr) * 32 + (fq << 3));
#pragma unroll
    for (int nn = 0; nn < 4; ++nn)
      bfr[nn] = *(const bf16x8*)(Bs + ((wc << 6) + (nn << 4) + fr) * 32 + (fq << 3));
#pragma unroll
    for (int m = 0; m < 4; ++m)
#pragma unroll
      for (int nn = 0; nn < 4; ++nn)
        acc[m][nn] = __builtin_amdgcn_mfma_f32_16x16x32_bf16(af[m], bfr[nn], acc[m][nn], 0, 0, 0);
    __syncthreads();
  }
#pragma unroll
  for (int m = 0; m < 4; ++m) {
#pragma unroll
    for (int nn = 0; nn < 4; ++nn) {
      const int col = n0 + (wc << 6) + (nn << 4) + fr;
      const float bv = doBias ? bias[col] : 0.f;
#pragma unroll
      for (int j = 0; j < 4; ++j) {
        const int row = m0 + (wr << 6) + (m << 4) + (fq << 2) + j;
        float vv = acc[m][nn][j] + bv;
        if (GELU) vv = 0.5f * vv * (1.0f + erff(vv * 0.70710678118654752f));
        if (OUTBF) outB[(size_t)row * N + col] = __float2bfloat16(vv);
        else       outP[(size_t)row * N + col] = vv;
      }
    }
  }
}

// ---------- encoder-decoder attention: one block per (n,h), 4-deep ring + counted vmcnt ----------
// dp2[q,s] = (k[n,h,s,:] . qc[n,h,q,:]) * 0.125 ; softmax over s ; out = P@V
// R7 compute structure (KVBLK=32, staged gll16 -> ideal FETCH; split-dot phase 1; p/ql
// wave-local) but the 2-deep dbuf + __syncthreads() (vmcnt(0) drain per tile) is replaced
// by a 4-tile ring with counted vmcnt: per tile, s_waitcnt vmcnt(4) waits ONLY tile u's
// own 2 loads -- tiles u+1,u+2 stay in flight ACROSS the barrier (never drain to 0).
// Unified 64-tile loop: u<32 = K/scores, u>=32 = V/PV; softmax at u==32 (wave-local, no
// extra sync). Safety: each wave waits its own vmcnt then barriers => after barrier all
// waves' tile-u loads landed; STAGE(u+3) overwrites buffer last read in iter u-1, fenced
// by the same barrier. LDS = 4x8KB ring + 16KB p + 1KB ql = 49KB -> 3 blocks/CU.
__global__ __launch_bounds__(256) void k_attn(
    const float* __restrict__ kk, const float* __restrict__ vvg,
    const float* __restrict__ qc1, const float* __restrict__ qc2,
    __hip_bfloat16* __restrict__ wa2b)
{
  __shared__ __align__(16) float tile[4][32 * 64];  // 4 x 8KB ring
  __shared__ float p[4 * 1024];                     // 16KB scores (per-wave rows)
  __shared__ __align__(16) float ql[4 * 64];        // 1KB q
  const int tid = threadIdx.x;
  const int wave = tid >> 6, lane = tid & 63;
  const int n = blockIdx.x >> 4, h = blockIdx.x & 15;
  const size_t kvbase = (size_t)(n * 16 + h) * (1024 * 64);

  // q tile -> LDS (wave-local write+read)
  {
    const size_t qidx = ((size_t)wave * 1024 + n) * 1024 + h * 64 + lane;
    ql[tid] = (qc1[qidx] + qc2[qidx]) * 0.125f;
  }
  const float* qrow = ql + wave * 64;

  // STAGE tile u (32 rows, 8KB): 8 gll16 total, 2 per wave; 16B slot g of row r holds
  // source word-quad (g ^ (r&15)) -> balanced banks on the swizzled reads below.
  auto STAGE = [&](int u) {
    const float* __restrict__ src = (u < 32) ? kk : vvg;
    const int s0 = (u & 31) << 5;
#pragma unroll
    for (int i = 0; i < 2; ++i) {
      const int chunk = (wave << 1) + i;            // 0..7, 4 rows each
      const int rl = (chunk << 2) + (lane >> 4);    // row 0..31
      const int slot = (lane & 15) ^ (rl & 15);     // pre-swizzled source
      gll16(src + kvbase + (size_t)(s0 + rl) * 64 + (slot << 2), tile[u & 3] + (chunk << 8));
    }
  };

  STAGE(0); STAGE(1); STAGE(2);                     // prologue: 3 tiles in flight

  const int sl = lane & 31;
  const int dbase = (lane >> 5) << 3;               // 0 or 8
  const int sxx = sl & 15;
  const int sg = lane >> 4, e4 = lane & 15;
  float4 acc4 = make_float4(0.f, 0.f, 0.f, 0.f);
  float inv = 0.f;

  for (int u = 0; u < 64; ++u) {
    // wait own tile-u loads only (keep u+1,u+2 in flight), then block-sync
    if (u < 62)       asm volatile("s_waitcnt vmcnt(4)" ::: "memory");
    else if (u == 62) asm volatile("s_waitcnt vmcnt(2)" ::: "memory");
    else              asm volatile("s_waitcnt vmcnt(0)" ::: "memory");
    __builtin_amdgcn_s_barrier();
    if (u < 61) STAGE(u + 3);                       // refill ring (writes buf read in iter u-1)
    const float* tl = tile[u & 3];
    if (u < 32) {
      // scores: sl = s-row, lane>>5 = d-half; shfl_xor(32) combines halves
      float a = 0.f;
#pragma unroll
      for (int j = 0; j < 8; ++j) {
        const int c = dbase + j;
        const float4 kv = *(const float4*)(tl + sl * 64 + ((c ^ sxx) << 2));
        const float4 qa = *(const float4*)(qrow + (c << 2));
        a += kv.x * qa.x + kv.y * qa.y + kv.z * qa.z + kv.w * qa.w;
      }
      a += __shfl_xor(a, 32);
      if (lane < 32) p[(wave << 10) + (u << 5) + sl] = a;
    } else {
      if (u == 32) {
        // softmax over s (wave-local p, own-wave writes in program order)
        float mx = -1e30f;
#pragma unroll
        for (int j = 0; j < 16; ++j) mx = fmaxf(mx, p[(wave << 10) + (j << 6) + lane]);
#pragma unroll
        for (int o = 32; o; o >>= 1) mx = fmaxf(mx, __shfl_xor(mx, o));
        float sum = 0.f;
#pragma unroll
        for (int j = 0; j < 16; ++j) {
          const float e = __expf(p[(wave << 10) + (j << 6) + lane] - mx);
          p[(wave << 10) + (j << 6) + lane] = e;
          sum += e;
        }
#pragma unroll
        for (int o = 32; o; o >>= 1) sum += __shfl_xor(sum, o);
        inv = 1.0f / sum;
      }
      // P @ V : lane = sg*16 + e4 ; rows s = so*4+sg, float4 over e
      const float* prow = p + (wave << 10) + ((u - 32) << 5);
#pragma unroll
      for (int so = 0; so < 8; ++so) {
        const int s = (so << 2) + sg;
        const float pw = prow[s];                   // 4-addr LDS broadcast
        const float4 vv = *(const float4*)(tl + s * 64 + ((e4 ^ (s & 15)) << 2));
        acc4.x += pw * vv.x; acc4.y += pw * vv.y; acc4.z += pw * vv.z; acc4.w += pw * vv.w;
      }
    }
  }
  // reduce across sg groups (lanes lane, lane^16, lane^32, lane^48)
#pragma unroll
  for (int o = 16; o <= 32; o <<= 1) {
    acc4.x += __shfl_xor(acc4.x, o); acc4.y += __shfl_xor(acc4.y, o);
    acc4.z += __shfl_xor(acc4.z, o); acc4.w += __shfl_xor(acc4.w, o);
  }
  if (sg == 0) {
    ushort4 u4;
    u4.x = bf16bits(acc4.x * inv); u4.y = bf16bits(acc4.y * inv);
    u4.z = bf16bits(acc4.z * inv); u4.w = bf16bits(acc4.w * inv);
    *(ushort4*)(wa2b + ((size_t)wave * 1024 + n) * 1024 + h * 64 + (e4 << 2)) = u4;
  }
}

extern "C" void kernel_launch(void* const* d_in, const int* in_sizes, int n_in,
                              void* d_out, int out_size, void* d_ws, size_t ws_size,
                              hipStream_t stream)
{
  (void)in_sizes; (void)n_in; (void)out_size; (void)ws_size;
  const float* x     = (const float*)d_in[0];
  const float* kin   = (const float*)d_in[1];
  const float* vin   = (const float*)d_in[2];
  const float* qkv_w = (const float*)d_in[3];
  const float* qkv_b = (const float*)d_in[4];
  const float* sa_w  = (const float*)d_in[5];
  const float* sa_b  = (const float*)d_in[6];
  const float* q_w   = (const float*)d_in[7];
  const float* q_b   = (const float*)d_in[8];
  const float* ed_w  = (const float*)d_in[9];
  const float* ed_b  = (const float*)d_in[10];
  const float* fc1_w = (const float*)d_in[11];
  const float* fc1_b = (const float*)d_in[12];
  const float* fc2_w = (const float*)d_in[13];
  const float* fc2_b = (const float*)d_in[14];
  const float* ln1_w = (const float*)d_in[15];
  const float* ln1_b = (const float*)d_in[16];
  const float* ln2_w = (const float*)d_in[17];
  const float* ln2_b = (const float*)d_in[18];
  const float* ln3_w = (const float*)d_in[19];
  const float* ln3_b = (const float*)d_in[20];
  float* out = (float*)d_out;

  char* ws = (char*)d_ws;
  constexpr size_t MB = 1024ull * 1024ull;
  float* part  = (float*)(ws + 0);                       // 128 KB
  float* tmpt  = (float*)(ws + 192 * 1024);              // 4 KB
  float* sarow = (float*)(ws + 256 * 1024);              // 4 KB
  float* bufA  = (float*)(ws + 1 * MB);                  // 16 MB: qc1 -> ca1 -> z1
  float* bufB  = (float*)(ws + 17 * MB);                 // 16 MB: qc2 -> ca2 -> z2
  __hip_bfloat16* h1b  = (__hip_bfloat16*)(ws + 33 * MB);         // 8 MB -> wa2b after qc GEMM
  float*          h2   = (float*)(ws + 41 * MB);                  // 16 MB
  __hip_bfloat16* h2b  = (__hip_bfloat16*)(ws + 57 * MB);         // 8 MB
  __hip_bfloat16* g    = (__hip_bfloat16*)(ws + 65 * MB);         // 32 MB
  __hip_bfloat16* qwT  = (__hip_bfloat16*)(ws + 97 * MB);         // 2 MB
  __hip_bfloat16* edwT = (__hip_bfloat16*)(ws + 99 * MB);         // 2 MB
  __hip_bfloat16* f1wT = (__hip_bfloat16*)(ws + 101 * MB);        // 8 MB
  __hip_bfloat16* f2wT = (__hip_bfloat16*)(ws + 109 * MB);        // 8 MB (total 117 MB)
  __hip_bfloat16* wa2b = h1b;    // h1b dead after q-projection GEMM

  // all weight transposes in one launch
  k_transpose4<<<dim3(10240), 256, 0, stream>>>(q_w, qwT, ed_w, edwT, fc1_w, f1wT, fc2_w, f2wT);
  // self-attention algebraic collapse -> sa_row (3 launches)
  k_colsum_part<<<dim3(4, 32), 256, 0, stream>>>(x, part);
  k_matvec_t<<<dim3(32), 256, 0, stream>>>(part, qkv_w, tmpt);
  k_matvec_sa<<<dim3(32), 256, 0, stream>>>(tmpt, qkv_b, sa_w, sa_b, sarow);
  // h1 = LN1(x + sa_row) -> bf16
  k_ln<<<dim3(4096), 256, 0, stream>>>(x, nullptr, nullptr, sarow, ln1_w, ln1_b, nullptr, h1b);
  // qc = h1 @ q_w + q_b  (split-K x2 -> qc1,qc2)
  k_gemm_bt<0, 0><<<dim3(8, 32, 2), 256, 0, stream>>>(h1b, qwT, q_b, bufA, bufB, nullptr, 4096, 1024, 1024);
  // streaming cross-attention over k,v (8.6 GB) -> wa2 (bf16)
  k_attn<<<dim3(16384), 256, 0, stream>>>(kin, vin, bufA, bufB, wa2b);
  // ca = wa2 @ ed_proj_w + ed_proj_b  (split-K x2 -> ca1,ca2)
  k_gemm_bt<0, 0><<<dim3(8, 32, 2), 256, 0, stream>>>(wa2b, edwT, ed_b, bufA, bufB, nullptr, 4096, 1024, 1024);
  // h2 = LN2(ca1 + ca2 + x) -> fp32 + bf16
  k_ln<<<dim3(4096), 256, 0, stream>>>(bufA, bufB, x, nullptr, ln2_w, ln2_b, h2, h2b);
  // g = GELU(h2 @ fc1_w + fc1_b) -> bf16
  k_gemm_bt<1, 1><<<dim3(32, 32), 256, 0, stream>>>(h2b, f1wT, fc1_b, nullptr, nullptr, g, 4096, 4096, 1024);
  // z = g @ fc2_w + fc2_b  (split-K x2 -> z1,z2)
  k_gemm_bt<0, 0><<<dim3(8, 32, 2), 256, 0, stream>>>(g, f2wT, fc2_b, bufA, bufB, nullptr, 4096, 1024, 4096);
  // out = LN3(z1 + z2 + h2)
  k_ln<<<dim3(4096), 256, 0, stream>>>(bufA, bufB, h2, nullptr, ln3_w, ln3_b, out, nullptr);
}

// Round 9
// 1761.698 us; speedup vs baseline: 1.0757x; 1.0757x over previous
//
#include <hip/hip_runtime.h>
#include <hip/hip_bf16.h>
#include <math.h>

// Shapes (fixed): B=4, N=1024, SK=1024, D=1024, H=16, HD=64
typedef __attribute__((ext_vector_type(8))) short bf16x8;   // 8 bf16 (4 VGPRs)
typedef __attribute__((ext_vector_type(4))) float f32x4;

__device__ __forceinline__ void gll16(const void* g, const void* l) {
  // async global->LDS, 16B per lane; LDS dest = wave-uniform base + lane*16
  __builtin_amdgcn_global_load_lds((__attribute__((address_space(1))) void*)g,
                                   (__attribute__((address_space(3))) void*)l, 16, 0, 0);
}

__device__ __forceinline__ unsigned short bf16bits(float f) {
  __hip_bfloat16 h = __float2bfloat16(f);
  return *reinterpret_cast<unsigned short*>(&h);
}

__device__ __forceinline__ float bf2f(unsigned short u) {
  unsigned int x = ((unsigned int)u) << 16;
  float f;
  __builtin_memcpy(&f, &x, 4);
  return f;
}

// ---------- fused transpose of all 4 weight mats: fp32 (R x C) -> bf16 (C x R) ----------
__global__ __launch_bounds__(256) void k_transpose4(
    const float* __restrict__ W0, __hip_bfloat16* __restrict__ T0,
    const float* __restrict__ W1, __hip_bfloat16* __restrict__ T1,
    const float* __restrict__ W2, __hip_bfloat16* __restrict__ T2,
    const float* __restrict__ W3, __hip_bfloat16* __restrict__ T3)
{
  __shared__ float t[32][33];
  int b = blockIdx.x;
  const float* W; __hip_bfloat16* T; int R, C, bx, by;
  if (b < 1024)      { W = W0; T = T0; R = 1024; C = 1024; bx = b & 31;  by = b >> 5; }
  else if (b < 2048) { b -= 1024; W = W1; T = T1; R = 1024; C = 1024; bx = b & 31;  by = b >> 5; }
  else if (b < 6144) { b -= 2048; W = W2; T = T2; R = 1024; C = 4096; bx = b & 127; by = b >> 7; }
  else               { b -= 6144; W = W3; T = T3; R = 4096; C = 1024; bx = b & 31;  by = b >> 5; }
  const int c0 = bx << 5, r0 = by << 5;
  const int tx = threadIdx.x & 31, ty = threadIdx.x >> 5;  // ty 0..7
#pragma unroll
  for (int i = 0; i < 32; i += 8)
    t[ty + i][tx] = W[(size_t)(r0 + ty + i) * C + c0 + tx];
  __syncthreads();
#pragma unroll
  for (int i = 0; i < 32; i += 8)
    T[(size_t)(c0 + ty + i) * R + r0 + tx] = __float2bfloat16(t[tx][ty + i]);
}

// ---------- partial column sums of x: part[y][d] = sum_{r in y-th 128 rows} x[r][d] ----------
__global__ __launch_bounds__(256) void k_colsum_part(const float* __restrict__ x, float* __restrict__ part) {
  const int d = blockIdx.x * 256 + threadIdx.x;
  const int r0 = blockIdx.y * 128;
  float acc = 0.f;
  for (int r = 0; r < 128; ++r) acc += x[(size_t)(r0 + r) * 1024 + d];
  part[blockIdx.y * 1024 + d] = acc;
}

// ---------- t[j] = sum_d Xsum[d] * qkv_w[d][2048+j]  (Xsum recomputed in-block from part) ----------
__global__ __launch_bounds__(256) void k_matvec_t(const float* __restrict__ part,
                                                  const float* __restrict__ qkv_w,
                                                  float* __restrict__ tmpt) {
  __shared__ float xs[1024];
  __shared__ float red[8][32];
#pragma unroll
  for (int jj = 0; jj < 4; ++jj) {
    const int d = threadIdx.x + (jj << 8);
    float a = 0.f;
    for (int y = 0; y < 32; ++y) a += part[y * 1024 + d];
    xs[d] = a;
  }
  __syncthreads();
  const int j = blockIdx.x * 32 + (threadIdx.x & 31);
  const int rg = threadIdx.x >> 5;
  float acc = 0.f;
  for (int r = rg; r < 1024; r += 8)
    acc += xs[r] * qkv_w[(size_t)r * 3072 + 2048 + j];
  red[rg][threadIdx.x & 31] = acc;
  __syncthreads();
  if (threadIdx.x < 32) {
    float s = 0.f;
    for (int gq = 0; gq < 8; ++gq) s += red[gq][threadIdx.x];
    tmpt[blockIdx.x * 32 + threadIdx.x] = s;
  }
}

// ---------- sa_row[j] = sum_i Vsum[i&63]*sa_w[i][j] + sa_b[j]  (Vsum recomputed in-block) ----------
__global__ __launch_bounds__(256) void k_matvec_sa(const float* __restrict__ tmpt,
                                                   const float* __restrict__ qkv_b,
                                                   const float* __restrict__ saw,
                                                   const float* __restrict__ sab,
                                                   float* __restrict__ sarow) {
  __shared__ float vs[64];
  __shared__ float red[8][32];
  if (threadIdx.x < 64) {
    float a = 0.f;
    for (int h = 0; h < 16; ++h)
      a += tmpt[h * 64 + threadIdx.x] + 4096.0f * qkv_b[2048 + h * 64 + threadIdx.x];
    vs[threadIdx.x] = a;
  }
  __syncthreads();
  const int j = blockIdx.x * 32 + (threadIdx.x & 31);
  const int rg = threadIdx.x >> 5;
  float acc = 0.f;
  for (int r = rg; r < 1024; r += 8)
    acc += vs[r & 63] * saw[(size_t)r * 1024 + j];
  red[rg][threadIdx.x & 31] = acc;
  __syncthreads();
  if (threadIdx.x < 32) {
    float s = 0.f;
    for (int gq = 0; gq < 8; ++gq) s += red[gq][threadIdx.x];
    sarow[blockIdx.x * 32 + threadIdx.x] = s + sab[blockIdx.x * 32 + threadIdx.x];
  }
}

// ---------- LayerNorm (per-row, D=1024), float4-vectorized ----------
// y = LN(a [+b] [+c_fp32] [+cb_bf16] [+rowadd]) * w + bias ; outputs fp32 and/or bf16
__global__ __launch_bounds__(256) void k_ln(
    const float* __restrict__ a, const float* __restrict__ b, const float* __restrict__ c,
    const __hip_bfloat16* __restrict__ cb,
    const float* __restrict__ rowadd, const float* __restrict__ w,
    const float* __restrict__ bias, float* __restrict__ outF,
    __hip_bfloat16* __restrict__ outB)
{
  const size_t base = (size_t)blockIdx.x * 1024;
  const int d4 = threadIdx.x << 2;
  float4 t = *(const float4*)(a + base + d4);
  if (b) { const float4 u = *(const float4*)(b + base + d4);
           t.x += u.x; t.y += u.y; t.z += u.z; t.w += u.w; }
  if (c) { const float4 u = *(const float4*)(c + base + d4);
           t.x += u.x; t.y += u.y; t.z += u.z; t.w += u.w; }
  if (cb) { const ushort4 u = *(const ushort4*)(cb + base + d4);
            t.x += bf2f(u.x); t.y += bf2f(u.y); t.z += bf2f(u.z); t.w += bf2f(u.w); }
  if (rowadd) { const float4 u = *(const float4*)(rowadd + d4);
                t.x += u.x; t.y += u.y; t.z += u.z; t.w += u.w; }
  float s1 = t.x + t.y + t.z + t.w;
  float s2 = t.x * t.x + t.y * t.y + t.z * t.z + t.w * t.w;
#pragma unroll
  for (int o = 32; o; o >>= 1) { s1 += __shfl_xor(s1, o); s2 += __shfl_xor(s2, o); }
  __shared__ float r1[4], r2[4];
  const int wv = threadIdx.x >> 6;
  if ((threadIdx.x & 63) == 0) { r1[wv] = s1; r2[wv] = s2; }
  __syncthreads();
  s1 = r1[0] + r1[1] + r1[2] + r1[3];
  s2 = r2[0] + r2[1] + r2[2] + r2[3];
  const float mean = s1 * (1.0f / 1024.0f);
  const float var = s2 * (1.0f / 1024.0f) - mean * mean;
  const float inv = rsqrtf(var + 1e-6f);
  const float4 w4 = *(const float4*)(w + d4);
  const float4 b4 = *(const float4*)(bias + d4);
  const float y0 = (t.x - mean) * inv * w4.x + b4.x;
  const float y1 = (t.y - mean) * inv * w4.y + b4.y;
  const float y2 = (t.z - mean) * inv * w4.z + b4.z;
  const float y3 = (t.w - mean) * inv * w4.w + b4.w;
  if (outF) *(float4*)(outF + base + d4) = make_float4(y0, y1, y2, y3);
  if (outB) {
    ushort4 u4; u4.x = bf16bits(y0); u4.y = bf16bits(y1); u4.z = bf16bits(y2); u4.w = bf16bits(y3);
    *(ushort4*)(outB + base + d4) = u4;
  }
}

// ---------- bf16 MFMA GEMM: C[M,N] = A[M,K] @ BT[N,K]^T + bias (m97 structure) ----------
// split-K via gridDim.z: z=0 -> outF+bias, z=1 -> outF2 no bias
template<int GELU, int OUTBF>
__global__ __launch_bounds__(256) void k_gemm_bt(
    const __hip_bfloat16* __restrict__ A, const __hip_bfloat16* __restrict__ BT,
    const float* __restrict__ bias, float* __restrict__ outF, float* __restrict__ outF2,
    __hip_bfloat16* __restrict__ outB, int M, int N, int K)
{
  __shared__ __align__(16) __hip_bfloat16 As[128 * 32];
  __shared__ __align__(16) __hip_bfloat16 Bs[128 * 32];
  const int tid = threadIdx.x;
  const int wave = tid >> 6, lane = tid & 63;
  const int m0 = blockIdx.y << 7, n0 = blockIdx.x << 7;
  const int kl = K / gridDim.z;
  const int ks = blockIdx.z * kl;
  float* outP = blockIdx.z ? outF2 : outF;
  const bool doBias = (blockIdx.z == 0);
  const int wr = wave >> 1, wc = wave & 1;         // 64x64 wave tile
  const int fr = lane & 15, fq = lane >> 4;
  f32x4 acc[4][4] = {};
  const int srow = (lane >> 2);                    // 0..15 within chunk
  const int scol = (lane & 3) * 8;                 // bf16 col offset
  for (int k0 = ks; k0 < ks + kl; k0 += 32) {
#pragma unroll
    for (int i = 0; i < 2; ++i) {
      const int chunk = wave * 2 + i;              // 0..7: 16 rows each
      const int row = (chunk << 4) + srow;
      gll16(A + (size_t)(m0 + row) * K + k0 + scol, As + (chunk << 9));
      gll16(BT + (size_t)(n0 + row) * K + k0 + scol, Bs + (chunk << 9));
    }
    __syncthreads();
    bf16x8 af[4], bfr[4];
#pragma unroll
    for (int m = 0; m < 4; ++m)
      af[m] = *(const bf16x8*)(As + ((wr << 6) + (m << 4) + fr) * 32 + (fq << 3));
#pragma unroll
    for (int nn = 0; nn < 4; ++nn)
      bfr[nn] = *(const bf16x8*)(Bs + ((wc << 6) + (nn << 4) + fr) * 32 + (fq << 3));
#pragma unroll
    for (int m = 0; m < 4; ++m)
#pragma unroll
      for (int nn = 0; nn < 4; ++nn)
        acc[m][nn] = __builtin_amdgcn_mfma_f32_16x16x32_bf16(af[m], bfr[nn], acc[m][nn], 0, 0, 0);
    __syncthreads();
  }
#pragma unroll
  for (int m = 0; m < 4; ++m) {
#pragma unroll
    for (int nn = 0; nn < 4; ++nn) {
      const int col = n0 + (wc << 6) + (nn << 4) + fr;
      const float bv = doBias ? bias[col] : 0.f;
#pragma unroll
      for (int j = 0; j < 4; ++j) {
        const int row = m0 + (wr << 6) + (m << 4) + (fq << 2) + j;
        float vv = acc[m][nn][j] + bv;
        if (GELU) vv = 0.5f * vv * (1.0f + erff(vv * 0.70710678118654752f));
        if (OUTBF) outB[(size_t)row * N + col] = __float2bfloat16(vv);
        else       outP[(size_t)row * N + col] = vv;
      }
    }
  }
}

// ---------- encoder-decoder attention: one block per (n,h), double-buffered, KVBLK=32 ----------
// dp2[q,s] = (k[n,h,s,:] . qc[n,h,q,:]) * 0.125 ; softmax over s ; out = P@V
// PROVEN structure (R3/R7 = 1768 us): staged gll16 tiles (ideal 8.6GB FETCH), 2-deep
// double buffer with __syncthreads per tile, p/ql wave-local, no q VGPR hoist.
// Refuted alternatives (keep for the record): direct-global (R6: 2.5x FETCH), register
// scores (R5: -128us), 4-deep counted-vmcnt ring (R8: -126us), occupancy 3->4 (R7: =).
// Attn sustains ~5.81 TB/s = 92% of the 6.29 TB/s copy ceiling -> at fabric limit.
__global__ __launch_bounds__(256) void k_attn(
    const float* __restrict__ kk, const float* __restrict__ vvg,
    const float* __restrict__ qc1, const float* __restrict__ qc2,
    __hip_bfloat16* __restrict__ wa2b)
{
  __shared__ __align__(16) float tile[2][32 * 64];  // 2 x 8KB double buffer
  __shared__ float p[4 * 1024];                     // 16KB scores (per-wave rows)
  __shared__ __align__(16) float ql[4 * 64];        // 1KB q
  const int tid = threadIdx.x;
  const int wave = tid >> 6, lane = tid & 63;
  const int n = blockIdx.x >> 4, h = blockIdx.x & 15;
  const size_t kvbase = (size_t)(n * 16 + h) * (1024 * 64);

  // q tile -> LDS (wave-local write+read)
  {
    const size_t qidx = ((size_t)wave * 1024 + n) * 1024 + h * 64 + lane;
    ql[tid] = (qc1[qidx] + qc2[qidx]) * 0.125f;
  }
  const float* qrow = ql + wave * 64;

  // STAGE a 32-row (8KB) tile: 8 gll16 total, 2 per wave; 16B slot g of row r holds
  // source word-quad (g ^ (r&15)) -> balanced banks on the swizzled reads below.
  auto STAGE = [&](const float* __restrict__ src, int bi, int s0) {
#pragma unroll
    for (int i = 0; i < 2; ++i) {
      const int chunk = (wave << 1) + i;            // 0..7, 4 rows each
      const int rl = (chunk << 2) + (lane >> 4);    // row 0..31
      const int slot = (lane & 15) ^ (rl & 15);     // pre-swizzled source
      gll16(src + kvbase + (size_t)(s0 + rl) * 64 + (slot << 2), tile[bi] + (chunk << 8));
    }
  };

  STAGE(kk, 0, 0);
  __syncthreads();

  // ---- phase 1: scores; wave = q; sl=lane&31 -> s-row, lane>>5 -> d-half ----
  const int sl = lane & 31;
  const int dbase = (lane >> 5) << 3;               // 0 or 8
  const int sxx = sl & 15;
  for (int t = 0; t < 32; ++t) {
    if (t < 31) STAGE(kk, (t + 1) & 1, (t + 1) << 5);
    else        STAGE(vvg, 0, 0);                   // prefetch V tile 0 over softmax
    const float* tl = tile[t & 1];
    float a = 0.f;
#pragma unroll
    for (int j = 0; j < 8; ++j) {
      const int c = dbase + j;
      const float4 kv = *(const float4*)(tl + sl * 64 + ((c ^ sxx) << 2));
      const float4 qa = *(const float4*)(qrow + (c << 2));   // 2-addr LDS broadcast
      a += kv.x * qa.x + kv.y * qa.y + kv.z * qa.z + kv.w * qa.w;
    }
    a += __shfl_xor(a, 32);                         // combine d-halves
    if (lane < 32) p[(wave << 10) + (t << 5) + sl] = a;
    __syncthreads();
  }

  // ---- softmax over s (wave-local p, no barriers) ----
  float mx = -1e30f;
#pragma unroll
  for (int j = 0; j < 16; ++j) mx = fmaxf(mx, p[(wave << 10) + (j << 6) + lane]);
#pragma unroll
  for (int o = 32; o; o >>= 1) mx = fmaxf(mx, __shfl_xor(mx, o));
  float sum = 0.f;
#pragma unroll
  for (int j = 0; j < 16; ++j) {
    const float e = __expf(p[(wave << 10) + (j << 6) + lane] - mx);
    p[(wave << 10) + (j << 6) + lane] = e;
    sum += e;
  }
#pragma unroll
  for (int o = 32; o; o >>= 1) sum += __shfl_xor(sum, o);
  const float inv = 1.0f / sum;                     // uniform across wave

  // ---- phase 2: P @ V ; lane = sg*16 + e4 ; rows s = so*4+sg, float4 over e ----
  const int sg = lane >> 4, e4 = lane & 15;
  float4 acc4 = make_float4(0.f, 0.f, 0.f, 0.f);
  for (int t = 0; t < 32; ++t) {
    if (t < 31) STAGE(vvg, (t + 1) & 1, (t + 1) << 5);
    const float* tl = tile[t & 1];
    const float* prow = p + (wave << 10) + (t << 5);
#pragma unroll
    for (int so = 0; so < 8; ++so) {
      const int s = (so << 2) + sg;
      const float pw = prow[s];                     // 4-addr LDS broadcast
      const float4 vv = *(const float4*)(tl + s * 64 + ((e4 ^ (s & 15)) << 2));
      acc4.x += pw * vv.x; acc4.y += pw * vv.y; acc4.z += pw * vv.z; acc4.w += pw * vv.w;
    }
    __syncthreads();
  }
  // reduce across sg groups (lanes lane, lane^16, lane^32, lane^48)
#pragma unroll
  for (int o = 16; o <= 32; o <<= 1) {
    acc4.x += __shfl_xor(acc4.x, o); acc4.y += __shfl_xor(acc4.y, o);
    acc4.z += __shfl_xor(acc4.z, o); acc4.w += __shfl_xor(acc4.w, o);
  }
  if (sg == 0) {
    ushort4 u4;
    u4.x = bf16bits(acc4.x * inv); u4.y = bf16bits(acc4.y * inv);
    u4.z = bf16bits(acc4.z * inv); u4.w = bf16bits(acc4.w * inv);
    *(ushort4*)(wa2b + ((size_t)wave * 1024 + n) * 1024 + h * 64 + (e4 << 2)) = u4;
  }
}

extern "C" void kernel_launch(void* const* d_in, const int* in_sizes, int n_in,
                              void* d_out, int out_size, void* d_ws, size_t ws_size,
                              hipStream_t stream)
{
  (void)in_sizes; (void)n_in; (void)out_size; (void)ws_size;
  const float* x     = (const float*)d_in[0];
  const float* kin   = (const float*)d_in[1];
  const float* vin   = (const float*)d_in[2];
  const float* qkv_w = (const float*)d_in[3];
  const float* qkv_b = (const float*)d_in[4];
  const float* sa_w  = (const float*)d_in[5];
  const float* sa_b  = (const float*)d_in[6];
  const float* q_w   = (const float*)d_in[7];
  const float* q_b   = (const float*)d_in[8];
  const float* ed_w  = (const float*)d_in[9];
  const float* ed_b  = (const float*)d_in[10];
  const float* fc1_w = (const float*)d_in[11];
  const float* fc1_b = (const float*)d_in[12];
  const float* fc2_w = (const float*)d_in[13];
  const float* fc2_b = (const float*)d_in[14];
  const float* ln1_w = (const float*)d_in[15];
  const float* ln1_b = (const float*)d_in[16];
  const float* ln2_w = (const float*)d_in[17];
  const float* ln2_b = (const float*)d_in[18];
  const float* ln3_w = (const float*)d_in[19];
  const float* ln3_b = (const float*)d_in[20];
  float* out = (float*)d_out;

  char* ws = (char*)d_ws;
  constexpr size_t MB = 1024ull * 1024ull;
  float* part  = (float*)(ws + 0);                       // 128 KB
  float* tmpt  = (float*)(ws + 192 * 1024);              // 4 KB
  float* sarow = (float*)(ws + 256 * 1024);              // 4 KB
  float* bufA  = (float*)(ws + 1 * MB);                  // 16 MB: qc1 -> ca1 -> z1
  float* bufB  = (float*)(ws + 17 * MB);                 // 16 MB: qc2 -> ca2 -> z2
  __hip_bfloat16* h1b  = (__hip_bfloat16*)(ws + 33 * MB);         // 8 MB -> wa2b after qc GEMM
  __hip_bfloat16* h2b  = (__hip_bfloat16*)(ws + 57 * MB);         // 8 MB (fp32 h2 eliminated)
  __hip_bfloat16* g    = (__hip_bfloat16*)(ws + 65 * MB);         // 32 MB
  __hip_bfloat16* qwT  = (__hip_bfloat16*)(ws + 97 * MB);         // 2 MB
  __hip_bfloat16* edwT = (__hip_bfloat16*)(ws + 99 * MB);         // 2 MB
  __hip_bfloat16* f1wT = (__hip_bfloat16*)(ws + 101 * MB);        // 8 MB
  __hip_bfloat16* f2wT = (__hip_bfloat16*)(ws + 109 * MB);        // 8 MB (total 117 MB)
  __hip_bfloat16* wa2b = h1b;    // h1b dead after q-projection GEMM

  // all weight transposes in one launch
  k_transpose4<<<dim3(10240), 256, 0, stream>>>(q_w, qwT, ed_w, edwT, fc1_w, f1wT, fc2_w, f2wT);
  // self-attention algebraic collapse -> sa_row (3 launches)
  k_colsum_part<<<dim3(4, 32), 256, 0, stream>>>(x, part);
  k_matvec_t<<<dim3(32), 256, 0, stream>>>(part, qkv_w, tmpt);
  k_matvec_sa<<<dim3(32), 256, 0, stream>>>(tmpt, qkv_b, sa_w, sa_b, sarow);
  // h1 = LN1(x + sa_row) -> bf16
  k_ln<<<dim3(4096), 256, 0, stream>>>(x, nullptr, nullptr, nullptr, sarow, ln1_w, ln1_b, nullptr, h1b);
  // qc = h1 @ q_w + q_b  (split-K x2 -> qc1,qc2)
  k_gemm_bt<0, 0><<<dim3(8, 32, 2), 256, 0, stream>>>(h1b, qwT, q_b, bufA, bufB, nullptr, 4096, 1024, 1024);
  // streaming cross-attention over k,v (8.6 GB) -> wa2 (bf16)
  k_attn<<<dim3(16384), 256, 0, stream>>>(kin, vin, bufA, bufB, wa2b);
  // ca = wa2 @ ed_proj_w + ed_proj_b  (split-K x2 -> ca1,ca2)
  k_gemm_bt<0, 0><<<dim3(8, 32, 2), 256, 0, stream>>>(wa2b, edwT, ed_b, bufA, bufB, nullptr, 4096, 1024, 1024);
  // h2 = LN2(ca1 + ca2 + x) -> bf16 only (LN3 residual reads the bf16 copy)
  k_ln<<<dim3(4096), 256, 0, stream>>>(bufA, bufB, x, nullptr, nullptr, ln2_w, ln2_b, nullptr, h2b);
  // g = GELU(h2 @ fc1_w + fc1_b) -> bf16
  k_gemm_bt<1, 1><<<dim3(32, 32), 256, 0, stream>>>(h2b, f1wT, fc1_b, nullptr, nullptr, g, 4096, 4096, 1024);
  // z = g @ fc2_w + fc2_b  (split-K x2 -> z1,z2)
  k_gemm_bt<0, 0><<<dim3(8, 32, 2), 256, 0, stream>>>(g, f2wT, fc2_b, bufA, bufB, nullptr, 4096, 1024, 4096);
  // out = LN3(z1 + z2 + h2b)
  k_ln<<<dim3(4096), 256, 0, stream>>>(bufA, bufB, nullptr, h2b, nullptr, ln3_w, ln3_b, out, nullptr);
}